// Round 18
// baseline (181.276 us; speedup 1.0000x reference)
//
#include <hip/hip_runtime.h>
#include <math.h>

// ---------------------------------------------------------------------------
// EncoderCS: emb-gather -> relu(emb@W_enc+b) -> self-attn (no-diag softmax)
//            -> ctx -> gate=sigmoid([h;ctx]@W_g+b) -> out=gate*h, row-means.
// All GEMMs via v_mfma_f32_32x32x16_bf16 (fp32 accum).
// R18: ht (transposed h) now produced inside k_enc's epilogue via a 2-phase
//      LDS transpose (tlx[128][130], bijective stride, bank-clean readout) —
//      k_htrans eliminated (~64MB shuttle). k_cvt_all+k_trans_both merged
//      into one k_prep launch. GEMM structure frozen at R17 (181 us):
//      2-phase loops at 3 blocks/CU + XCD-chunked swizzles (FETCH ~= unique
//      bytes everywhere) — measured plateau of this schedule family.
// ---------------------------------------------------------------------------

typedef __attribute__((ext_vector_type(4)))  float f32x4v;
typedef __attribute__((ext_vector_type(16))) float f32x16v;
typedef __attribute__((ext_vector_type(8)))  short bf16x8v;

typedef const unsigned int __attribute__((address_space(1)))* as1_cuint_p;
typedef unsigned int __attribute__((address_space(3)))* as3_uint_p;

#define MFMA32(A_, B_, C_) __builtin_amdgcn_mfma_f32_32x32x16_bf16((A_), (B_), (C_), 0, 0, 0)

static __device__ __forceinline__ void vmwait0() {
  asm volatile("s_waitcnt vmcnt(0)" ::: "memory");
}

static __device__ __forceinline__ short f2bf(float f) {
  unsigned u = __float_as_uint(f);
  u = (u + 0x7fffu + ((u >> 16) & 1u)) >> 16;   // RNE
  return (short)u;
}
static __device__ __forceinline__ float bf2f(short h) {
  return __uint_as_float(((unsigned)(unsigned short)h) << 16);
}
static __device__ __forceinline__ f32x16v fzero16() {
  f32x16v z;
  for (int i = 0; i < 16; ++i) z[i] = 0.0f;
  return z;
}

// T1: bijective chunked XCD swizzle (nwg % 8 == 0).
static __device__ __forceinline__ int xcd_swz(int bid, int nwg) {
  return (bid & 7) * (nwg >> 3) + (bid >> 3);
}

// 16B global->LDS direct (HW: dest = wave-uniform base + lane*16).
static __device__ __forceinline__ void gload16(const short* g, short* l) {
  __builtin_amdgcn_global_load_lds((as1_cuint_p)g, (as3_uint_p)l, 16, 0, 0);
}

// Stage ITERS*32 rows x 64 k bf16 from row-major src (rstride shorts) into
// linear LDS [rows][64]. Source granule inverse-swizzled (g ^= row&7).
template <int ITERS>
static __device__ __forceinline__ void stage_rows(const short* __restrict__ src,
                                                  size_t rstride, int r0, int kk,
                                                  short* dstLDS, int t) {
  short* lbase = dstLDS + (t >> 6) * 512;  // wave-uniform base (shorts)
#pragma unroll
  for (int i = 0; i < ITERS; ++i) {
    int row = (t >> 3) + i * 32;
    int c = (t & 7) ^ (row & 7);
    gload16(src + (size_t)(r0 + row) * rstride + kk + c * 8, lbase + i * 2048);
  }
}

// MFMA inner block (128x128 tile): As/Bs [128][64], wave (wm,wn) of 2x2.
static __device__ __forceinline__ void mfma_block(const short* As, const short* Bs,
                                                  f32x16v acc[2][2],
                                                  int lr, int lh, int wm, int wn) {
  const char* Ab = (const char*)As + (64 * wm + lr) * 128;
  const char* Bb = (const char*)Bs + (64 * wn + lr) * 128;
  int sw = lr & 7;
#pragma unroll
  for (int kc = 0; kc < 4; ++kc) {
    int off = ((lh + 2 * kc) ^ sw) << 4;
    bf16x8v a0 = *(const bf16x8v*)(Ab + off);
    bf16x8v a1 = *(const bf16x8v*)(Ab + 32 * 128 + off);
    bf16x8v b0 = *(const bf16x8v*)(Bb + off);
    bf16x8v b1 = *(const bf16x8v*)(Bb + 32 * 128 + off);
    acc[0][0] = MFMA32(a0, b0, acc[0][0]);
    acc[0][1] = MFMA32(a0, b1, acc[0][1]);
    acc[1][0] = MFMA32(a1, b0, acc[1][0]);
    acc[1][1] = MFMA32(a1, b1, acc[1][1]);
  }
}

// MFMA inner block (256x128 tile): As [256][64], Bs [128][64]. 4 waves as
// 2M x 2N; per-wave output 128x64 = acc[4][2] 32x32 frags.
static __device__ __forceinline__ void mfma_block2(const short* As, const short* Bs,
                                                   f32x16v acc[4][2],
                                                   int lr, int lh, int wm, int wn) {
  const char* Ab = (const char*)As + (128 * wm + lr) * 128;
  const char* Bb = (const char*)Bs + (64 * wn + lr) * 128;
  int sw = lr & 7;
#pragma unroll
  for (int kc = 0; kc < 4; ++kc) {
    int off = ((lh + 2 * kc) ^ sw) << 4;
    bf16x8v b0 = *(const bf16x8v*)(Bb + off);
    bf16x8v b1 = *(const bf16x8v*)(Bb + 32 * 128 + off);
#pragma unroll
    for (int a = 0; a < 4; ++a) {
      bf16x8v av = *(const bf16x8v*)(Ab + a * 32 * 128 + off);
      acc[a][0] = MFMA32(av, b0, acc[a][0]);
      acc[a][1] = MFMA32(av, b1, acc[a][1]);
    }
  }
}

// ---- K_prep: table converts (f32->bf16) + both weight transposes --------
// Blocks [0,3753): cvt; [3753, 4521): 32x32 transpose tiles.
__global__ __launch_bounds__(256) void k_prep(
    const float* __restrict__ s0, short* __restrict__ d0,   // tp    640
    const float* __restrict__ s1, short* __restrict__ d1,   // ent   480000
    const float* __restrict__ s2, short* __restrict__ d2,   // val   480000
    const float* __restrict__ s3, short* __restrict__ d3,   // ha    48
    const float* __restrict__ w0, short* __restrict__ t0,   // W_enc 512x512
    const float* __restrict__ w1, short* __restrict__ t1) { // W_g  1024x512
  __shared__ float ls[32][33];
  if (blockIdx.x < 3753) {
    int i = blockIdx.x * 256 + threadIdx.x;
    const float* src;
    short* dst;
    if (i < 480000) { src = s1; dst = d1; }
    else if (i < 960000) { src = s2; dst = d2; i -= 480000; }
    else if (i < 960640) { src = s0; dst = d0; i -= 960000; }
    else if (i < 960688) { src = s3; dst = d3; i -= 960640; }
    else return;
    f32x4v v0 = *(const f32x4v*)(src + (size_t)i * 8);
    f32x4v v1 = *(const f32x4v*)(src + (size_t)i * 8 + 4);
    bf16x8v o;
    o[0] = f2bf(v0[0]); o[1] = f2bf(v0[1]); o[2] = f2bf(v0[2]); o[3] = f2bf(v0[3]);
    o[4] = f2bf(v1[0]); o[5] = f2bf(v1[1]); o[6] = f2bf(v1[2]); o[7] = f2bf(v1[3]);
    *(bf16x8v*)(dst + (size_t)i * 8) = o;
    return;
  }
  int bid = blockIdx.x - 3753;  // 768 tiles: [0,256) W_enc, [256,768) W_g
  const float* src;
  short* dst;
  int K, bx, by;
  if (bid < 256) { src = w0; dst = t0; K = 512; bx = bid & 15; by = bid >> 4; }
  else { bid -= 256; src = w1; dst = t1; K = 1024; bx = bid & 31; by = bid >> 5; }
  const int N = 512;
  int t = threadIdx.x, tx = t & 31, ty = t >> 5;
  int k0 = bx * 32, n0 = by * 32;
#pragma unroll
  for (int p = 0; p < 4; ++p)
    ls[ty + 8 * p][tx] = src[(size_t)(k0 + ty + 8 * p) * N + n0 + tx];
  __syncthreads();
#pragma unroll
  for (int p = 0; p < 4; ++p)
    dst[(size_t)(n0 + ty + 8 * p) * K + k0 + tx] = f2bf(ls[tx][ty + 8 * p]);
}

// ---- K1: gather emb(bf16) + enc GEMM + bias + relu -> h AND ht ----------
// 256x128 tile: 1D grid 512, XCD-swizzled n-FASTEST. Epilogue: 2-phase LDS
// transpose (tlx[128][130]) emits ht coalesced; k_htrans eliminated.
// Block 0 also zeroes lsum.
__global__ __launch_bounds__(256, 2) void k_enc(
    const int* __restrict__ types, const int* __restrict__ ents,
    const int* __restrict__ vals, const int* __restrict__ haa,
    const short* __restrict__ Etp, const short* __restrict__ Eent,
    const short* __restrict__ Eval, const short* __restrict__ Eha,
    const short* __restrict__ Wt, const float* __restrict__ benc,
    short* __restrict__ h, short* __restrict__ ht, float* __restrict__ lsum) {
  __shared__ __align__(16) short lds[24576];  // GEMM: As|Bs; epilogue: tlx
  __shared__ int idx[4][256];
  short* As = lds;
  short* Bs = lds + 16384;
  int t = threadIdx.x;
  if (blockIdx.x == 0) {
    f32x4v z4;
    z4[0] = z4[1] = z4[2] = z4[3] = 0.0f;
    for (int i = t; i < 8192; i += 256) *(f32x4v*)(lsum + (size_t)i * 4) = z4;
  }
  int wgid = xcd_swz(blockIdx.x, 512);
  int m0 = (wgid >> 2) * 256, n0 = (wgid & 3) * 128;
  int b_ = m0 >> 10, s0 = m0 & 1023;
  for (int i = t; i < 1024; i += 256) {
    int tb = i >> 8, rr = i & 255, g = m0 + rr;
    int v;
    if (tb == 0) v = types[g];
    else if (tb == 1) v = ents[g];
    else if (tb == 2) v = vals[g];
    else v = haa[g];
    idx[tb][rr] = v;
  }
  int lane = t & 63, wid = t >> 6, lr = lane & 31, lh = lane >> 5;
  int wm = wid >> 1, wn = wid & 1;
  f32x16v acc[4][2];
#pragma unroll
  for (int a = 0; a < 4; ++a)
#pragma unroll
    for (int bb = 0; bb < 2; ++bb) acc[a][bb] = fzero16();

  for (int kk = 0; kk < 512; kk += 64) {
    __syncthreads();
    {  // stage A: gathered bf16 table rows, inverse-swizzled source granule
      int tb = kk >> 7, koff = kk & 127;
      const short* tbl = (tb == 0) ? Etp : (tb == 1) ? Eent : (tb == 2) ? Eval : Eha;
      short* lbase = As + wid * 512;
#pragma unroll
      for (int i = 0; i < 8; ++i) {
        int row = (t >> 3) + i * 32;
        int c = (t & 7) ^ (row & 7);
        gload16(tbl + (size_t)idx[tb][row] * 128 + koff + c * 8, lbase + i * 2048);
      }
    }
    stage_rows<4>(Wt, 512, n0, kk, Bs, t);
    vmwait0();
    __syncthreads();
    mfma_block2(As, Bs, acc, lr, lh, wm, wn);
  }
  __syncthreads();          // all GEMM LDS reads done; lds reused as tlx
  short* tlx = lds;         // [128 n][130] bf16 — bijective, bank-clean
#pragma unroll
  for (int p = 0; p < 2; ++p) {
    if (wm == p) {
#pragma unroll
      for (int a = 0; a < 4; ++a)
#pragma unroll
        for (int bb = 0; bb < 2; ++bb) {
          int col = 64 * wn + 32 * bb + lr;
          int n = n0 + col;
          float bias = benc[n];
#pragma unroll
          for (int r = 0; r < 16; ++r) {
            int rloc = 32 * a + (r & 3) + 8 * (r >> 2) + 4 * lh;
            int m = m0 + 128 * p + rloc;
            short pb = f2bf(fmaxf(acc[a][bb][r] + bias, 0.0f));
            h[(size_t)m * 512 + n] = pb;
            tlx[col * 130 + rloc] = pb;
          }
        }
    }
    __syncthreads();
    {  // coalesced ht write: thread t -> n row t>>1, 64-short half (t&1)
      int n_loc = t >> 1, off = (t & 1) * 64;
      const short* srcl = tlx + n_loc * 130 + off;
      short* dstp = ht + (size_t)b_ * 524288 + (size_t)(n0 + n_loc) * 1024 +
                    s0 + 128 * p + off;
#pragma unroll
      for (int v = 0; v < 8; ++v)
        *(bf16x8v*)(dstp + v * 8) = *(const bf16x8v*)(srcl + v * 8);
    }
    __syncthreads();
  }
}

// ---- K2a: scores + exp -> P (unnormalized, diag=0) + lsum ---------------
// Symmetric 36 pairs x 32 batches, 1D grid 1152, XCD-swizzled (4 batches
// per XCD -> h L2-resident). Row/col sums from the P-write tile re-reads.
__global__ __launch_bounds__(256, 2) void k_scores(const short* __restrict__ h,
                                                   short* __restrict__ P,
                                                   float* __restrict__ lsum) {
  __shared__ __align__(16) short lds[16640];
  short* As = lds;
  short* Bs = lds + 8192;
  int t = threadIdx.x;
  int wgid = xcd_swz(blockIdx.x, 1152);
  int b = wgid / 36;
  int pid = wgid - b * 36, mt = 0;
  while (pid >= 8 - mt) { pid -= 8 - mt; ++mt; }
  int nt = mt + pid;
  int m0 = mt * 128, n0 = nt * 128;
  const short* hb = h + (size_t)b * 524288;
  int lane = t & 63, wid = t >> 6, lr = lane & 31, lh = lane >> 5;
  int wm = wid >> 1, wn = wid & 1;
  f32x16v acc[2][2];
#pragma unroll
  for (int a = 0; a < 2; ++a)
#pragma unroll
    for (int bb = 0; bb < 2; ++bb) acc[a][bb] = fzero16();

  for (int kk = 0; kk < 512; kk += 64) {
    __syncthreads();
    stage_rows<4>(hb, 512, m0, kk, As, t);
    stage_rows<4>(hb, 512, n0, kk, Bs, t);
    vmwait0();
    __syncthreads();
    mfma_block(As, Bs, acc, lr, lh, wm, wn);
  }
  __syncthreads();
  short* tl = lds;            // [128][130] bf16 — stride > 128: bijective
  bool diag = (mt == nt);
  float* lsb = lsum + (size_t)b * 1024;
#pragma unroll
  for (int a = 0; a < 2; ++a) {
#pragma unroll
    for (int r = 0; r < 16; ++r) {
      int row_loc = 64 * wm + 32 * a + (r & 3) + 8 * (r >> 2) + 4 * lh;
      int rg = m0 + row_loc;
#pragma unroll
      for (int bb = 0; bb < 2; ++bb) {
        int j_loc = 64 * wn + 32 * bb + lr;
        int j = n0 + j_loc;
        float s = acc[a][bb][r];
        tl[row_loc * 130 + j_loc] = (j == rg) ? (short)0 : f2bf(__expf(s));
      }
    }
  }
  __syncthreads();
  {  // straight tile: coalesced 16B stores + row sums
    int row = t >> 1, half = (t & 1) * 64;
    short* dst = P + ((size_t)(b * 1024 + m0 + row)) * 1024 + n0 + half;
    const short* srcl = tl + row * 130 + half;
    float rs = 0.0f;
#pragma unroll
    for (int v = 0; v < 8; ++v) {
      bf16x8v o = *(const bf16x8v*)(srcl + v * 8);
#pragma unroll
      for (int e = 0; e < 8; ++e) rs += bf2f(o[e]);
      *(bf16x8v*)(dst + v * 8) = o;
    }
    rs += __shfl_xor(rs, 1, 64);
    if ((t & 1) == 0) atomicAdd(&lsb[m0 + row], rs);
  }
  if (!diag) {  // mirror: transposed read from tl + column sums
    int jr = t >> 1, ch = (t & 1) * 64;
    short* dst = P + ((size_t)(b * 1024 + n0 + jr)) * 1024 + m0 + ch;
    float cs = 0.0f;
#pragma unroll
    for (int v = 0; v < 8; ++v) {
      bf16x8v o;
#pragma unroll
      for (int e = 0; e < 8; ++e) {
        short pv = tl[(ch + v * 8 + e) * 130 + jr];
        o[e] = pv;
        cs += bf2f(pv);
      }
      *(bf16x8v*)(dst + v * 8) = o;
    }
    cs += __shfl_xor(cs, 1, 64);
    if ((t & 1) == 0) atomicAdd(&lsb[n0 + jr], cs);
  }
}

// ---- K2b: ctx = (P @ h_b) / l -> ctx bf16 [32768][512] ------------------
// 256x128 tile: 1D grid 512, XCD-swizzled (4 batches per XCD, nt fastest).
__global__ __launch_bounds__(256, 2) void k_ctx(const short* __restrict__ P,
                                                const short* __restrict__ ht,
                                                const float* __restrict__ lsum,
                                                short* __restrict__ ctx) {
  __shared__ __align__(16) short lds[24576];  // As 16384 | Bs 8192
  short* As = lds;
  short* Bs = lds + 16384;
  int t = threadIdx.x;
  int wgid = xcd_swz(blockIdx.x, 512);
  int b = wgid >> 4, mt = (wgid >> 2) & 3, nt = wgid & 3;
  int m0 = mt * 256, n0 = nt * 128;
  int lane = t & 63, wid = t >> 6, lr = lane & 31, lh = lane >> 5;
  int wm = wid >> 1, wn = wid & 1;
  f32x16v acc[4][2];
#pragma unroll
  for (int a = 0; a < 4; ++a)
#pragma unroll
    for (int bb = 0; bb < 2; ++bb) acc[a][bb] = fzero16();

  const short* Pb = P + (size_t)b * 1048576;
  const short* htb = ht + (size_t)b * 524288;
  for (int kk = 0; kk < 1024; kk += 64) {
    __syncthreads();
    stage_rows<8>(Pb, 1024, m0, kk, As, t);
    stage_rows<4>(htb, 1024, n0, kk, Bs, t);
    vmwait0();
    __syncthreads();
    mfma_block2(As, Bs, acc, lr, lh, wm, wn);
  }
#pragma unroll
  for (int a = 0; a < 4; ++a)
#pragma unroll
    for (int r = 0; r < 16; ++r) {
      int m = m0 + 128 * wm + 32 * a + (r & 3) + 8 * (r >> 2) + 4 * lh;
      float linv = 1.0f / lsum[(size_t)b * 1024 + m];
#pragma unroll
      for (int bb = 0; bb < 2; ++bb) {
        int n = n0 + 64 * wn + 32 * bb + lr;
        ctx[((size_t)(b * 1024 + m)) * 512 + n] = f2bf(acc[a][bb][r] * linv);
      }
    }
}

// ---- K3: gate = sigmoid([h;ctx]@W_g+b), out = gate*h, col partial sums --
// 256x128 tile: 1D grid 512, XCD-swizzled n-FASTEST.
__global__ __launch_bounds__(256, 2) void k_gate(const short* __restrict__ h,
                                                 const short* __restrict__ ctx,
                                                 const short* __restrict__ Wgt,
                                                 const float* __restrict__ bg,
                                                 float* __restrict__ out,
                                                 float* __restrict__ part) {
  __shared__ __align__(16) short lds[24576];  // As 16384 | Bs 8192
  __shared__ float partc[2][128];
  short* As = lds;
  short* Bs = lds + 16384;
  int t = threadIdx.x;
  int wgid = xcd_swz(blockIdx.x, 512);
  int m0 = (wgid >> 2) * 256, n0 = (wgid & 3) * 128;
  int lane = t & 63, wid = t >> 6, lr = lane & 31, lh = lane >> 5;
  int wm = wid >> 1, wn = wid & 1;
  f32x16v acc[4][2];
#pragma unroll
  for (int a = 0; a < 4; ++a)
#pragma unroll
    for (int bb = 0; bb < 2; ++bb) acc[a][bb] = fzero16();

  for (int kk = 0; kk < 1024; kk += 64) {
    __syncthreads();
    const short* Asrc = (kk < 512) ? h : ctx;
    stage_rows<8>(Asrc, 512, m0, kk & 511, As, t);
    stage_rows<4>(Wgt, 1024, n0, kk, Bs, t);
    vmwait0();
    __syncthreads();
    mfma_block2(As, Bs, acc, lr, lh, wm, wn);
  }
  float cs[2] = {0.0f, 0.0f};
#pragma unroll
  for (int a = 0; a < 4; ++a)
#pragma unroll
    for (int bb = 0; bb < 2; ++bb) {
      int n = n0 + 64 * wn + 32 * bb + lr;
      float bias = bg[n];
#pragma unroll
      for (int r = 0; r < 16; ++r) {
        int m = m0 + 128 * wm + 32 * a + (r & 3) + 8 * (r >> 2) + 4 * lh;
        float x = acc[a][bb][r] + bias;
        float g = 1.0f / (1.0f + __expf(-x));
        float hv = bf2f(h[(size_t)m * 512 + n]);
        float o = g * hv;
        out[(size_t)m * 512 + n] = o;
        cs[bb] += o;
      }
    }
#pragma unroll
  for (int bb = 0; bb < 2; ++bb) {
    cs[bb] += __shfl_xor(cs[bb], 32, 64);
    if (lh == 0) partc[wm][64 * wn + 32 * bb + lr] = cs[bb];
  }
  __syncthreads();
  if (t < 256) {
    int half = t >> 7, col = t & 127;
    int b = m0 >> 10, si = ((m0 >> 7) & 7) + half;
    part[(size_t)(si * 32 + b) * 512 + n0 + col] = partc[half][col];
  }
}

// ---- K4: final means, written as 4 identical outputs --------------------
__global__ __launch_bounds__(512) void k_avg_fin(const float* __restrict__ part,
                                                 float* __restrict__ avg) {
  int b = blockIdx.x, n = threadIdx.x;
  float s = 0.0f;
#pragma unroll
  for (int si = 0; si < 8; ++si) s += part[(size_t)(si * 32 + b) * 512 + n];
  s *= (1.0f / 1024.0f);
#pragma unroll
  for (int i = 0; i < 4; ++i) avg[(size_t)i * 16384 + b * 512 + n] = s;
}

// ---- workspace layout (bytes) -------------------------------------------
#define WS_H 0
#define WS_HT 33554432
#define WS_CTX 67108864          // also hosts bf16 tables until k_enc is done
#define WS_LSUM 100663296
#define WS_WT 100794368
#define WS_WGT 101318656
#define WS_PART 102367232
// total required: 102,891,520 bytes (~98.1 MiB)
// bf16 tables inside the CTX region (dead until k_ctx writes it):
#define CTX_ETP 0
#define CTX_EENT 10240
#define CTX_EVAL 7690240
#define CTX_EHA 15370240

extern "C" void kernel_launch(void* const* d_in, const int* in_sizes, int n_in,
                              void* d_out, int out_size, void* d_ws, size_t ws_size,
                              hipStream_t stream) {
  const int* types = (const int*)d_in[0];
  const int* ents = (const int*)d_in[1];
  const int* vals = (const int*)d_in[2];
  const int* haa = (const int*)d_in[3];
  const float* E_tp = (const float*)d_in[4];
  const float* E_ent = (const float*)d_in[5];
  const float* E_val = (const float*)d_in[6];
  const float* E_ha = (const float*)d_in[7];
  const float* W_enc = (const float*)d_in[8];
  const float* benc = (const float*)d_in[9];
  const float* W_g = (const float*)d_in[10];
  const float* bg = (const float*)d_in[11];
  float* out = (float*)d_out;

  char* ws = (char*)d_ws;
  short* h = (short*)(ws + WS_H);        // bf16 [32768][512]
  short* ht = (short*)(ws + WS_HT);      // bf16 [32][512][1024]
  short* ctx = (short*)(ws + WS_CTX);    // bf16 [32768][512]
  float* lsum = (float*)(ws + WS_LSUM);  // f32  [32][1024]
  short* Wt = (short*)(ws + WS_WT);      // bf16 [512][512]   (W_enc^T)
  short* Wgt = (short*)(ws + WS_WGT);    // bf16 [512][1024]  (W_g^T)
  float* part = (float*)(ws + WS_PART);  // f32  [8][32][512]
  short* P = (short*)d_out;              // bf16 [32][1024][1024] in content region
  short* Etp = (short*)(ws + WS_CTX + CTX_ETP);
  short* Eent = (short*)(ws + WS_CTX + CTX_EENT);
  short* Eval = (short*)(ws + WS_CTX + CTX_EVAL);
  short* Eha = (short*)(ws + WS_CTX + CTX_EHA);

  k_prep<<<dim3(4521), 256, 0, stream>>>(E_tp, Etp, E_ent, Eent, E_val, Eval,
                                         E_ha, Eha, W_enc, Wt, W_g, Wgt);
  k_enc<<<dim3(512), 256, 0, stream>>>(types, ents, vals, haa, Etp, Eent, Eval,
                                       Eha, Wt, benc, h, ht, lsum);
  k_scores<<<dim3(1152), 256, 0, stream>>>(h, P, lsum);
  k_ctx<<<dim3(512), 256, 0, stream>>>(P, ht, lsum, ctx);
  k_gate<<<dim3(512), 256, 0, stream>>>(h, ctx, Wgt, bg, out, part);
  k_avg_fin<<<dim3(32), 512, 0, stream>>>(part, out + 16777216);
}

// Round 19
// 178.813 us; speedup vs baseline: 1.0138x; 1.0138x over previous
//
#include <hip/hip_runtime.h>
#include <math.h>

// ---------------------------------------------------------------------------
// EncoderCS: emb-gather -> relu(emb@W_enc+b) -> self-attn (no-diag softmax)
//            -> ctx -> gate=sigmoid([h;ctx]@W_g+b) -> out=gate*h, row-means.
// All GEMMs via v_mfma_f32_32x32x16_bf16 (fp32 accum).
// R19: k_enc's fused ht transpose goes SINGLE-phase: tlx[128][260] (66.5KB,
//      still 2 blocks/CU = grid limit), all 4 waves write concurrently
//      (2-way bank aliasing = free), one barrier, one vector copy-out.
//      R18's two half-active phases + 4 barriers ate the k_htrans saving.
//      Rest frozen at R17/R18 (181 us).
// ---------------------------------------------------------------------------

typedef __attribute__((ext_vector_type(4)))  float f32x4v;
typedef __attribute__((ext_vector_type(16))) float f32x16v;
typedef __attribute__((ext_vector_type(8)))  short bf16x8v;

typedef const unsigned int __attribute__((address_space(1)))* as1_cuint_p;
typedef unsigned int __attribute__((address_space(3)))* as3_uint_p;

#define MFMA32(A_, B_, C_) __builtin_amdgcn_mfma_f32_32x32x16_bf16((A_), (B_), (C_), 0, 0, 0)

static __device__ __forceinline__ void vmwait0() {
  asm volatile("s_waitcnt vmcnt(0)" ::: "memory");
}

static __device__ __forceinline__ short f2bf(float f) {
  unsigned u = __float_as_uint(f);
  u = (u + 0x7fffu + ((u >> 16) & 1u)) >> 16;   // RNE
  return (short)u;
}
static __device__ __forceinline__ float bf2f(short h) {
  return __uint_as_float(((unsigned)(unsigned short)h) << 16);
}
static __device__ __forceinline__ f32x16v fzero16() {
  f32x16v z;
  for (int i = 0; i < 16; ++i) z[i] = 0.0f;
  return z;
}

// T1: bijective chunked XCD swizzle (nwg % 8 == 0).
static __device__ __forceinline__ int xcd_swz(int bid, int nwg) {
  return (bid & 7) * (nwg >> 3) + (bid >> 3);
}

// 16B global->LDS direct (HW: dest = wave-uniform base + lane*16).
static __device__ __forceinline__ void gload16(const short* g, short* l) {
  __builtin_amdgcn_global_load_lds((as1_cuint_p)g, (as3_uint_p)l, 16, 0, 0);
}

// Stage ITERS*32 rows x 64 k bf16 from row-major src (rstride shorts) into
// linear LDS [rows][64]. Source granule inverse-swizzled (g ^= row&7).
template <int ITERS>
static __device__ __forceinline__ void stage_rows(const short* __restrict__ src,
                                                  size_t rstride, int r0, int kk,
                                                  short* dstLDS, int t) {
  short* lbase = dstLDS + (t >> 6) * 512;  // wave-uniform base (shorts)
#pragma unroll
  for (int i = 0; i < ITERS; ++i) {
    int row = (t >> 3) + i * 32;
    int c = (t & 7) ^ (row & 7);
    gload16(src + (size_t)(r0 + row) * rstride + kk + c * 8, lbase + i * 2048);
  }
}

// MFMA inner block (128x128 tile): As/Bs [128][64], wave (wm,wn) of 2x2.
static __device__ __forceinline__ void mfma_block(const short* As, const short* Bs,
                                                  f32x16v acc[2][2],
                                                  int lr, int lh, int wm, int wn) {
  const char* Ab = (const char*)As + (64 * wm + lr) * 128;
  const char* Bb = (const char*)Bs + (64 * wn + lr) * 128;
  int sw = lr & 7;
#pragma unroll
  for (int kc = 0; kc < 4; ++kc) {
    int off = ((lh + 2 * kc) ^ sw) << 4;
    bf16x8v a0 = *(const bf16x8v*)(Ab + off);
    bf16x8v a1 = *(const bf16x8v*)(Ab + 32 * 128 + off);
    bf16x8v b0 = *(const bf16x8v*)(Bb + off);
    bf16x8v b1 = *(const bf16x8v*)(Bb + 32 * 128 + off);
    acc[0][0] = MFMA32(a0, b0, acc[0][0]);
    acc[0][1] = MFMA32(a0, b1, acc[0][1]);
    acc[1][0] = MFMA32(a1, b0, acc[1][0]);
    acc[1][1] = MFMA32(a1, b1, acc[1][1]);
  }
}

// MFMA inner block (256x128 tile): As [256][64], Bs [128][64]. 4 waves as
// 2M x 2N; per-wave output 128x64 = acc[4][2] 32x32 frags.
static __device__ __forceinline__ void mfma_block2(const short* As, const short* Bs,
                                                   f32x16v acc[4][2],
                                                   int lr, int lh, int wm, int wn) {
  const char* Ab = (const char*)As + (128 * wm + lr) * 128;
  const char* Bb = (const char*)Bs + (64 * wn + lr) * 128;
  int sw = lr & 7;
#pragma unroll
  for (int kc = 0; kc < 4; ++kc) {
    int off = ((lh + 2 * kc) ^ sw) << 4;
    bf16x8v b0 = *(const bf16x8v*)(Bb + off);
    bf16x8v b1 = *(const bf16x8v*)(Bb + 32 * 128 + off);
#pragma unroll
    for (int a = 0; a < 4; ++a) {
      bf16x8v av = *(const bf16x8v*)(Ab + a * 32 * 128 + off);
      acc[a][0] = MFMA32(av, b0, acc[a][0]);
      acc[a][1] = MFMA32(av, b1, acc[a][1]);
    }
  }
}

// ---- K_prep: table converts (f32->bf16) + both weight transposes --------
// Blocks [0,3753): cvt; [3753, 4521): 32x32 transpose tiles.
__global__ __launch_bounds__(256) void k_prep(
    const float* __restrict__ s0, short* __restrict__ d0,   // tp    640
    const float* __restrict__ s1, short* __restrict__ d1,   // ent   480000
    const float* __restrict__ s2, short* __restrict__ d2,   // val   480000
    const float* __restrict__ s3, short* __restrict__ d3,   // ha    48
    const float* __restrict__ w0, short* __restrict__ t0,   // W_enc 512x512
    const float* __restrict__ w1, short* __restrict__ t1) { // W_g  1024x512
  __shared__ float ls[32][33];
  if (blockIdx.x < 3753) {
    int i = blockIdx.x * 256 + threadIdx.x;
    const float* src;
    short* dst;
    if (i < 480000) { src = s1; dst = d1; }
    else if (i < 960000) { src = s2; dst = d2; i -= 480000; }
    else if (i < 960640) { src = s0; dst = d0; i -= 960000; }
    else if (i < 960688) { src = s3; dst = d3; i -= 960640; }
    else return;
    f32x4v v0 = *(const f32x4v*)(src + (size_t)i * 8);
    f32x4v v1 = *(const f32x4v*)(src + (size_t)i * 8 + 4);
    bf16x8v o;
    o[0] = f2bf(v0[0]); o[1] = f2bf(v0[1]); o[2] = f2bf(v0[2]); o[3] = f2bf(v0[3]);
    o[4] = f2bf(v1[0]); o[5] = f2bf(v1[1]); o[6] = f2bf(v1[2]); o[7] = f2bf(v1[3]);
    *(bf16x8v*)(dst + (size_t)i * 8) = o;
    return;
  }
  int bid = blockIdx.x - 3753;  // 768 tiles: [0,256) W_enc, [256,768) W_g
  const float* src;
  short* dst;
  int K, bx, by;
  if (bid < 256) { src = w0; dst = t0; K = 512; bx = bid & 15; by = bid >> 4; }
  else { bid -= 256; src = w1; dst = t1; K = 1024; bx = bid & 31; by = bid >> 5; }
  const int N = 512;
  int t = threadIdx.x, tx = t & 31, ty = t >> 5;
  int k0 = bx * 32, n0 = by * 32;
#pragma unroll
  for (int p = 0; p < 4; ++p)
    ls[ty + 8 * p][tx] = src[(size_t)(k0 + ty + 8 * p) * N + n0 + tx];
  __syncthreads();
#pragma unroll
  for (int p = 0; p < 4; ++p)
    dst[(size_t)(n0 + ty + 8 * p) * K + k0 + tx] = f2bf(ls[tx][ty + 8 * p]);
}

// ---- K1: gather emb(bf16) + enc GEMM + bias + relu -> h AND ht ----------
// 256x128 tile: 1D grid 512, XCD-swizzled n-FASTEST. Epilogue: SINGLE-phase
// LDS transpose tlx[128 n][260] (all waves write concurrently, 2-way bank
// aliasing = free), one barrier, one vector copy-out. Block 0 zeroes lsum.
__global__ __launch_bounds__(256, 2) void k_enc(
    const int* __restrict__ types, const int* __restrict__ ents,
    const int* __restrict__ vals, const int* __restrict__ haa,
    const short* __restrict__ Etp, const short* __restrict__ Eent,
    const short* __restrict__ Eval, const short* __restrict__ Eha,
    const short* __restrict__ Wt, const float* __restrict__ benc,
    short* __restrict__ h, short* __restrict__ ht, float* __restrict__ lsum) {
  __shared__ __align__(16) short lds[33280];  // GEMM As|Bs (24576 used);
                                              // epilogue tlx[128][260]
  __shared__ int idx[4][256];
  short* As = lds;
  short* Bs = lds + 16384;
  int t = threadIdx.x;
  if (blockIdx.x == 0) {
    f32x4v z4;
    z4[0] = z4[1] = z4[2] = z4[3] = 0.0f;
    for (int i = t; i < 8192; i += 256) *(f32x4v*)(lsum + (size_t)i * 4) = z4;
  }
  int wgid = xcd_swz(blockIdx.x, 512);
  int m0 = (wgid >> 2) * 256, n0 = (wgid & 3) * 128;
  int b_ = m0 >> 10, s0 = m0 & 1023;
  for (int i = t; i < 1024; i += 256) {
    int tb = i >> 8, rr = i & 255, g = m0 + rr;
    int v;
    if (tb == 0) v = types[g];
    else if (tb == 1) v = ents[g];
    else if (tb == 2) v = vals[g];
    else v = haa[g];
    idx[tb][rr] = v;
  }
  int lane = t & 63, wid = t >> 6, lr = lane & 31, lh = lane >> 5;
  int wm = wid >> 1, wn = wid & 1;
  f32x16v acc[4][2];
#pragma unroll
  for (int a = 0; a < 4; ++a)
#pragma unroll
    for (int bb = 0; bb < 2; ++bb) acc[a][bb] = fzero16();

  for (int kk = 0; kk < 512; kk += 64) {
    __syncthreads();
    {  // stage A: gathered bf16 table rows, inverse-swizzled source granule
      int tb = kk >> 7, koff = kk & 127;
      const short* tbl = (tb == 0) ? Etp : (tb == 1) ? Eent : (tb == 2) ? Eval : Eha;
      short* lbase = As + wid * 512;
#pragma unroll
      for (int i = 0; i < 8; ++i) {
        int row = (t >> 3) + i * 32;
        int c = (t & 7) ^ (row & 7);
        gload16(tbl + (size_t)idx[tb][row] * 128 + koff + c * 8, lbase + i * 2048);
      }
    }
    stage_rows<4>(Wt, 512, n0, kk, Bs, t);
    vmwait0();
    __syncthreads();
    mfma_block2(As, Bs, acc, lr, lh, wm, wn);
  }
  __syncthreads();          // all GEMM LDS reads done; lds reused as tlx
  short* tlx = lds;         // [128 n][260]: n-row holds 256 m values
#pragma unroll
  for (int a = 0; a < 4; ++a)
#pragma unroll
    for (int bb = 0; bb < 2; ++bb) {
      int col = 64 * wn + 32 * bb + lr;
      int n = n0 + col;
      float bias = benc[n];
#pragma unroll
      for (int r = 0; r < 16; ++r) {
        int rloc = 32 * a + (r & 3) + 8 * (r >> 2) + 4 * lh;
        int m = m0 + 128 * wm + rloc;
        short pb = f2bf(fmaxf(acc[a][bb][r] + bias, 0.0f));
        h[(size_t)m * 512 + n] = pb;
        tlx[col * 260 + 128 * wm + rloc] = pb;
      }
    }
  __syncthreads();
  {  // coalesced ht write: thread t -> n row t>>1, 128-short half (t&1)
    int n_loc = t >> 1, off = (t & 1) * 128;
    const short* srcl = tlx + n_loc * 260 + off;
    short* dstp = ht + (size_t)b_ * 524288 + (size_t)(n0 + n_loc) * 1024 + s0 + off;
#pragma unroll
    for (int v = 0; v < 16; ++v)
      *(bf16x8v*)(dstp + v * 8) = *(const bf16x8v*)(srcl + v * 8);
  }
}

// ---- K2a: scores + exp -> P (unnormalized, diag=0) + lsum ---------------
// Symmetric 36 pairs x 32 batches, 1D grid 1152, XCD-swizzled (4 batches
// per XCD -> h L2-resident). Row/col sums from the P-write tile re-reads.
__global__ __launch_bounds__(256, 2) void k_scores(const short* __restrict__ h,
                                                   short* __restrict__ P,
                                                   float* __restrict__ lsum) {
  __shared__ __align__(16) short lds[16640];
  short* As = lds;
  short* Bs = lds + 8192;
  int t = threadIdx.x;
  int wgid = xcd_swz(blockIdx.x, 1152);
  int b = wgid / 36;
  int pid = wgid - b * 36, mt = 0;
  while (pid >= 8 - mt) { pid -= 8 - mt; ++mt; }
  int nt = mt + pid;
  int m0 = mt * 128, n0 = nt * 128;
  const short* hb = h + (size_t)b * 524288;
  int lane = t & 63, wid = t >> 6, lr = lane & 31, lh = lane >> 5;
  int wm = wid >> 1, wn = wid & 1;
  f32x16v acc[2][2];
#pragma unroll
  for (int a = 0; a < 2; ++a)
#pragma unroll
    for (int bb = 0; bb < 2; ++bb) acc[a][bb] = fzero16();

  for (int kk = 0; kk < 512; kk += 64) {
    __syncthreads();
    stage_rows<4>(hb, 512, m0, kk, As, t);
    stage_rows<4>(hb, 512, n0, kk, Bs, t);
    vmwait0();
    __syncthreads();
    mfma_block(As, Bs, acc, lr, lh, wm, wn);
  }
  __syncthreads();
  short* tl = lds;            // [128][130] bf16 — stride > 128: bijective
  bool diag = (mt == nt);
  float* lsb = lsum + (size_t)b * 1024;
#pragma unroll
  for (int a = 0; a < 2; ++a) {
#pragma unroll
    for (int r = 0; r < 16; ++r) {
      int row_loc = 64 * wm + 32 * a + (r & 3) + 8 * (r >> 2) + 4 * lh;
      int rg = m0 + row_loc;
#pragma unroll
      for (int bb = 0; bb < 2; ++bb) {
        int j_loc = 64 * wn + 32 * bb + lr;
        int j = n0 + j_loc;
        float s = acc[a][bb][r];
        tl[row_loc * 130 + j_loc] = (j == rg) ? (short)0 : f2bf(__expf(s));
      }
    }
  }
  __syncthreads();
  {  // straight tile: coalesced 16B stores + row sums
    int row = t >> 1, half = (t & 1) * 64;
    short* dst = P + ((size_t)(b * 1024 + m0 + row)) * 1024 + n0 + half;
    const short* srcl = tl + row * 130 + half;
    float rs = 0.0f;
#pragma unroll
    for (int v = 0; v < 8; ++v) {
      bf16x8v o = *(const bf16x8v*)(srcl + v * 8);
#pragma unroll
      for (int e = 0; e < 8; ++e) rs += bf2f(o[e]);
      *(bf16x8v*)(dst + v * 8) = o;
    }
    rs += __shfl_xor(rs, 1, 64);
    if ((t & 1) == 0) atomicAdd(&lsb[m0 + row], rs);
  }
  if (!diag) {  // mirror: transposed read from tl + column sums
    int jr = t >> 1, ch = (t & 1) * 64;
    short* dst = P + ((size_t)(b * 1024 + n0 + jr)) * 1024 + m0 + ch;
    float cs = 0.0f;
#pragma unroll
    for (int v = 0; v < 8; ++v) {
      bf16x8v o;
#pragma unroll
      for (int e = 0; e < 8; ++e) {
        short pv = tl[(ch + v * 8 + e) * 130 + jr];
        o[e] = pv;
        cs += bf2f(pv);
      }
      *(bf16x8v*)(dst + v * 8) = o;
    }
    cs += __shfl_xor(cs, 1, 64);
    if ((t & 1) == 0) atomicAdd(&lsb[n0 + jr], cs);
  }
}

// ---- K2b: ctx = (P @ h_b) / l -> ctx bf16 [32768][512] ------------------
// 256x128 tile: 1D grid 512, XCD-swizzled (4 batches per XCD, nt fastest).
__global__ __launch_bounds__(256, 2) void k_ctx(const short* __restrict__ P,
                                                const short* __restrict__ ht,
                                                const float* __restrict__ lsum,
                                                short* __restrict__ ctx) {
  __shared__ __align__(16) short lds[24576];  // As 16384 | Bs 8192
  short* As = lds;
  short* Bs = lds + 16384;
  int t = threadIdx.x;
  int wgid = xcd_swz(blockIdx.x, 512);
  int b = wgid >> 4, mt = (wgid >> 2) & 3, nt = wgid & 3;
  int m0 = mt * 256, n0 = nt * 128;
  int lane = t & 63, wid = t >> 6, lr = lane & 31, lh = lane >> 5;
  int wm = wid >> 1, wn = wid & 1;
  f32x16v acc[4][2];
#pragma unroll
  for (int a = 0; a < 4; ++a)
#pragma unroll
    for (int bb = 0; bb < 2; ++bb) acc[a][bb] = fzero16();

  const short* Pb = P + (size_t)b * 1048576;
  const short* htb = ht + (size_t)b * 524288;
  for (int kk = 0; kk < 1024; kk += 64) {
    __syncthreads();
    stage_rows<8>(Pb, 1024, m0, kk, As, t);
    stage_rows<4>(htb, 1024, n0, kk, Bs, t);
    vmwait0();
    __syncthreads();
    mfma_block2(As, Bs, acc, lr, lh, wm, wn);
  }
#pragma unroll
  for (int a = 0; a < 4; ++a)
#pragma unroll
    for (int r = 0; r < 16; ++r) {
      int m = m0 + 128 * wm + 32 * a + (r & 3) + 8 * (r >> 2) + 4 * lh;
      float linv = 1.0f / lsum[(size_t)b * 1024 + m];
#pragma unroll
      for (int bb = 0; bb < 2; ++bb) {
        int n = n0 + 64 * wn + 32 * bb + lr;
        ctx[((size_t)(b * 1024 + m)) * 512 + n] = f2bf(acc[a][bb][r] * linv);
      }
    }
}

// ---- K3: gate = sigmoid([h;ctx]@W_g+b), out = gate*h, col partial sums --
// 256x128 tile: 1D grid 512, XCD-swizzled n-FASTEST.
__global__ __launch_bounds__(256, 2) void k_gate(const short* __restrict__ h,
                                                 const short* __restrict__ ctx,
                                                 const short* __restrict__ Wgt,
                                                 const float* __restrict__ bg,
                                                 float* __restrict__ out,
                                                 float* __restrict__ part) {
  __shared__ __align__(16) short lds[24576];  // As 16384 | Bs 8192
  __shared__ float partc[2][128];
  short* As = lds;
  short* Bs = lds + 16384;
  int t = threadIdx.x;
  int wgid = xcd_swz(blockIdx.x, 512);
  int m0 = (wgid >> 2) * 256, n0 = (wgid & 3) * 128;
  int lane = t & 63, wid = t >> 6, lr = lane & 31, lh = lane >> 5;
  int wm = wid >> 1, wn = wid & 1;
  f32x16v acc[4][2];
#pragma unroll
  for (int a = 0; a < 4; ++a)
#pragma unroll
    for (int bb = 0; bb < 2; ++bb) acc[a][bb] = fzero16();

  for (int kk = 0; kk < 1024; kk += 64) {
    __syncthreads();
    const short* Asrc = (kk < 512) ? h : ctx;
    stage_rows<8>(Asrc, 512, m0, kk & 511, As, t);
    stage_rows<4>(Wgt, 1024, n0, kk, Bs, t);
    vmwait0();
    __syncthreads();
    mfma_block2(As, Bs, acc, lr, lh, wm, wn);
  }
  float cs[2] = {0.0f, 0.0f};
#pragma unroll
  for (int a = 0; a < 4; ++a)
#pragma unroll
    for (int bb = 0; bb < 2; ++bb) {
      int n = n0 + 64 * wn + 32 * bb + lr;
      float bias = bg[n];
#pragma unroll
      for (int r = 0; r < 16; ++r) {
        int m = m0 + 128 * wm + 32 * a + (r & 3) + 8 * (r >> 2) + 4 * lh;
        float x = acc[a][bb][r] + bias;
        float g = 1.0f / (1.0f + __expf(-x));
        float hv = bf2f(h[(size_t)m * 512 + n]);
        float o = g * hv;
        out[(size_t)m * 512 + n] = o;
        cs[bb] += o;
      }
    }
#pragma unroll
  for (int bb = 0; bb < 2; ++bb) {
    cs[bb] += __shfl_xor(cs[bb], 32, 64);
    if (lh == 0) partc[wm][64 * wn + 32 * bb + lr] = cs[bb];
  }
  __syncthreads();
  if (t < 256) {
    int half = t >> 7, col = t & 127;
    int b = m0 >> 10, si = ((m0 >> 7) & 7) + half;
    part[(size_t)(si * 32 + b) * 512 + n0 + col] = partc[half][col];
  }
}

// ---- K4: final means, written as 4 identical outputs --------------------
__global__ __launch_bounds__(512) void k_avg_fin(const float* __restrict__ part,
                                                 float* __restrict__ avg) {
  int b = blockIdx.x, n = threadIdx.x;
  float s = 0.0f;
#pragma unroll
  for (int si = 0; si < 8; ++si) s += part[(size_t)(si * 32 + b) * 512 + n];
  s *= (1.0f / 1024.0f);
#pragma unroll
  for (int i = 0; i < 4; ++i) avg[(size_t)i * 16384 + b * 512 + n] = s;
}

// ---- workspace layout (bytes) -------------------------------------------
#define WS_H 0
#define WS_HT 33554432
#define WS_CTX 67108864          // also hosts bf16 tables until k_enc is done
#define WS_LSUM 100663296
#define WS_WT 100794368
#define WS_WGT 101318656
#define WS_PART 102367232
// total required: 102,891,520 bytes (~98.1 MiB)
// bf16 tables inside the CTX region (dead until k_ctx writes it):
#define CTX_ETP 0
#define CTX_EENT 10240
#define CTX_EVAL 7690240
#define CTX_EHA 15370240

extern "C" void kernel_launch(void* const* d_in, const int* in_sizes, int n_in,
                              void* d_out, int out_size, void* d_ws, size_t ws_size,
                              hipStream_t stream) {
  const int* types = (const int*)d_in[0];
  const int* ents = (const int*)d_in[1];
  const int* vals = (const int*)d_in[2];
  const int* haa = (const int*)d_in[3];
  const float* E_tp = (const float*)d_in[4];
  const float* E_ent = (const float*)d_in[5];
  const float* E_val = (const float*)d_in[6];
  const float* E_ha = (const float*)d_in[7];
  const float* W_enc = (const float*)d_in[8];
  const float* benc = (const float*)d_in[9];
  const float* W_g = (const float*)d_in[10];
  const float* bg = (const float*)d_in[11];
  float* out = (float*)d_out;

  char* ws = (char*)d_ws;
  short* h = (short*)(ws + WS_H);        // bf16 [32768][512]
  short* ht = (short*)(ws + WS_HT);      // bf16 [32][512][1024]
  short* ctx = (short*)(ws + WS_CTX);    // bf16 [32768][512]
  float* lsum = (float*)(ws + WS_LSUM);  // f32  [32][1024]
  short* Wt = (short*)(ws + WS_WT);      // bf16 [512][512]   (W_enc^T)
  short* Wgt = (short*)(ws + WS_WGT);    // bf16 [512][1024]  (W_g^T)
  float* part = (float*)(ws + WS_PART);  // f32  [8][32][512]
  short* P = (short*)d_out;              // bf16 [32][1024][1024] in content region
  short* Etp = (short*)(ws + WS_CTX + CTX_ETP);
  short* Eent = (short*)(ws + WS_CTX + CTX_EENT);
  short* Eval = (short*)(ws + WS_CTX + CTX_EVAL);
  short* Eha = (short*)(ws + WS_CTX + CTX_EHA);

  k_prep<<<dim3(4521), 256, 0, stream>>>(E_tp, Etp, E_ent, Eent, E_val, Eval,
                                         E_ha, Eha, W_enc, Wt, W_g, Wgt);
  k_enc<<<dim3(512), 256, 0, stream>>>(types, ents, vals, haa, Etp, Eent, Eval,
                                       Eha, Wt, benc, h, ht, lsum);
  k_scores<<<dim3(1152), 256, 0, stream>>>(h, P, lsum);
  k_ctx<<<dim3(512), 256, 0, stream>>>(P, ht, lsum, ctx);
  k_gate<<<dim3(512), 256, 0, stream>>>(h, ctx, Wgt, bg, out, part);
  k_avg_fin<<<dim3(32), 512, 0, stream>>>(part, out + 16777216);
}

// Round 20
// 176.307 us; speedup vs baseline: 1.0282x; 1.0142x over previous
//
#include <hip/hip_runtime.h>
#include <math.h>

// ---------------------------------------------------------------------------
// EncoderCS: emb-gather -> relu(emb@W_enc+b) -> self-attn (no-diag softmax)
//            -> ctx -> gate=sigmoid([h;ctx]@W_g+b) -> out=gate*h, row-means.
// All GEMMs via v_mfma_f32_32x32x16_bf16 (fp32 accum).
// R20: k_ctx/k_gate -> m201-geometry pipeline: 256x256 tile, 512thr/8 waves
//      (2Mx4N), 2x64KB LDS dbuf (128KB, 1 block/CU, grid 256 = no tail),
//      counted vmcnt(8) (never 0 until tail), raw-barrier/setprio schedule
//      with R16's proven-correct ordering. R16's failure was 4 waves/CU;
//      m201 shows 8 waves at 1 block/CU sustains 62% MfmaUtil.
//      k_enc/k_scores/k_prep frozen at R19 (178.8 us).
// ---------------------------------------------------------------------------

typedef __attribute__((ext_vector_type(4)))  float f32x4v;
typedef __attribute__((ext_vector_type(16))) float f32x16v;
typedef __attribute__((ext_vector_type(8)))  short bf16x8v;

typedef const unsigned int __attribute__((address_space(1)))* as1_cuint_p;
typedef unsigned int __attribute__((address_space(3)))* as3_uint_p;

#define MFMA32(A_, B_, C_) __builtin_amdgcn_mfma_f32_32x32x16_bf16((A_), (B_), (C_), 0, 0, 0)

static __device__ __forceinline__ void vmwait0() {
  asm volatile("s_waitcnt vmcnt(0)" ::: "memory");
}
static __device__ __forceinline__ void vmwait8() {
  asm volatile("s_waitcnt vmcnt(8)" ::: "memory");
}

static __device__ __forceinline__ short f2bf(float f) {
  unsigned u = __float_as_uint(f);
  u = (u + 0x7fffu + ((u >> 16) & 1u)) >> 16;   // RNE
  return (short)u;
}
static __device__ __forceinline__ float bf2f(short h) {
  return __uint_as_float(((unsigned)(unsigned short)h) << 16);
}
static __device__ __forceinline__ f32x16v fzero16() {
  f32x16v z;
  for (int i = 0; i < 16; ++i) z[i] = 0.0f;
  return z;
}

// T1: bijective chunked XCD swizzle (nwg % 8 == 0).
static __device__ __forceinline__ int xcd_swz(int bid, int nwg) {
  return (bid & 7) * (nwg >> 3) + (bid >> 3);
}

// 16B global->LDS direct (HW: dest = wave-uniform base + lane*16).
static __device__ __forceinline__ void gload16(const short* g, short* l) {
  __builtin_amdgcn_global_load_lds((as1_cuint_p)g, (as3_uint_p)l, 16, 0, 0);
}

// 256-thread stage: ITERS x 32 rows x 64 k, swizzled source granule.
template <int ITERS>
static __device__ __forceinline__ void stage_rows(const short* __restrict__ src,
                                                  size_t rstride, int r0, int kk,
                                                  short* dstLDS, int t) {
  short* lbase = dstLDS + (t >> 6) * 512;
#pragma unroll
  for (int i = 0; i < ITERS; ++i) {
    int row = (t >> 3) + i * 32;
    int c = (t & 7) ^ (row & 7);
    gload16(src + (size_t)(r0 + row) * rstride + kk + c * 8, lbase + i * 2048);
  }
}

// 512-thread stage: ITERS x 64 rows x 64 k, swizzled source granule.
template <int ITERS>
static __device__ __forceinline__ void stage512(const short* __restrict__ src,
                                                size_t rstride, int r0, int kk,
                                                short* dstLDS, int t) {
  short* lbase = dstLDS + (t >> 6) * 512;
#pragma unroll
  for (int i = 0; i < ITERS; ++i) {
    int row = (t >> 3) + i * 64;
    int c = (t & 7) ^ (row & 7);
    gload16(src + (size_t)(r0 + row) * rstride + kk + c * 8, lbase + i * 4096);
  }
}

// MFMA inner block (128x128 tile): As/Bs [128][64], wave (wm,wn) of 2x2.
static __device__ __forceinline__ void mfma_block(const short* As, const short* Bs,
                                                  f32x16v acc[2][2],
                                                  int lr, int lh, int wm, int wn) {
  const char* Ab = (const char*)As + (64 * wm + lr) * 128;
  const char* Bb = (const char*)Bs + (64 * wn + lr) * 128;
  int sw = lr & 7;
#pragma unroll
  for (int kc = 0; kc < 4; ++kc) {
    int off = ((lh + 2 * kc) ^ sw) << 4;
    bf16x8v a0 = *(const bf16x8v*)(Ab + off);
    bf16x8v a1 = *(const bf16x8v*)(Ab + 32 * 128 + off);
    bf16x8v b0 = *(const bf16x8v*)(Bb + off);
    bf16x8v b1 = *(const bf16x8v*)(Bb + 32 * 128 + off);
    acc[0][0] = MFMA32(a0, b0, acc[0][0]);
    acc[0][1] = MFMA32(a0, b1, acc[0][1]);
    acc[1][0] = MFMA32(a1, b0, acc[1][0]);
    acc[1][1] = MFMA32(a1, b1, acc[1][1]);
  }
}

// MFMA inner block, per-wave 128x64 output: A rows 128*wm.., B rows 64*wn..
// Works for 4-wave (wm2 x wn2) and 8-wave (wm2 x wn4) layouts. acc[4][2].
static __device__ __forceinline__ void mfma_block2(const short* As, const short* Bs,
                                                   f32x16v acc[4][2],
                                                   int lr, int lh, int wm, int wn) {
  const char* Ab = (const char*)As + (128 * wm + lr) * 128;
  const char* Bb = (const char*)Bs + (64 * wn + lr) * 128;
  int sw = lr & 7;
#pragma unroll
  for (int kc = 0; kc < 4; ++kc) {
    int off = ((lh + 2 * kc) ^ sw) << 4;
    bf16x8v b0 = *(const bf16x8v*)(Bb + off);
    bf16x8v b1 = *(const bf16x8v*)(Bb + 32 * 128 + off);
#pragma unroll
    for (int a = 0; a < 4; ++a) {
      bf16x8v av = *(const bf16x8v*)(Ab + a * 32 * 128 + off);
      acc[a][0] = MFMA32(av, b0, acc[a][0]);
      acc[a][1] = MFMA32(av, b1, acc[a][1]);
    }
  }
}

#define PIPE2_LDS 131072  // 2 bufs x (A 256x64 + B 256x64) bf16

// ---- K_prep: table converts (f32->bf16) + both weight transposes --------
__global__ __launch_bounds__(256) void k_prep(
    const float* __restrict__ s0, short* __restrict__ d0,   // tp    640
    const float* __restrict__ s1, short* __restrict__ d1,   // ent   480000
    const float* __restrict__ s2, short* __restrict__ d2,   // val   480000
    const float* __restrict__ s3, short* __restrict__ d3,   // ha    48
    const float* __restrict__ w0, short* __restrict__ t0,   // W_enc 512x512
    const float* __restrict__ w1, short* __restrict__ t1) { // W_g  1024x512
  __shared__ float ls[32][33];
  if (blockIdx.x < 3753) {
    int i = blockIdx.x * 256 + threadIdx.x;
    const float* src;
    short* dst;
    if (i < 480000) { src = s1; dst = d1; }
    else if (i < 960000) { src = s2; dst = d2; i -= 480000; }
    else if (i < 960640) { src = s0; dst = d0; i -= 960000; }
    else if (i < 960688) { src = s3; dst = d3; i -= 960640; }
    else return;
    f32x4v v0 = *(const f32x4v*)(src + (size_t)i * 8);
    f32x4v v1 = *(const f32x4v*)(src + (size_t)i * 8 + 4);
    bf16x8v o;
    o[0] = f2bf(v0[0]); o[1] = f2bf(v0[1]); o[2] = f2bf(v0[2]); o[3] = f2bf(v0[3]);
    o[4] = f2bf(v1[0]); o[5] = f2bf(v1[1]); o[6] = f2bf(v1[2]); o[7] = f2bf(v1[3]);
    *(bf16x8v*)(dst + (size_t)i * 8) = o;
    return;
  }
  int bid = blockIdx.x - 3753;  // 768 tiles: [0,256) W_enc, [256,768) W_g
  const float* src;
  short* dst;
  int K, bx, by;
  if (bid < 256) { src = w0; dst = t0; K = 512; bx = bid & 15; by = bid >> 4; }
  else { bid -= 256; src = w1; dst = t1; K = 1024; bx = bid & 31; by = bid >> 5; }
  const int N = 512;
  int t = threadIdx.x, tx = t & 31, ty = t >> 5;
  int k0 = bx * 32, n0 = by * 32;
#pragma unroll
  for (int p = 0; p < 4; ++p)
    ls[ty + 8 * p][tx] = src[(size_t)(k0 + ty + 8 * p) * N + n0 + tx];
  __syncthreads();
#pragma unroll
  for (int p = 0; p < 4; ++p)
    dst[(size_t)(n0 + ty + 8 * p) * K + k0 + tx] = f2bf(ls[tx][ty + 8 * p]);
}

// ---- K1: gather emb(bf16) + enc GEMM + bias + relu -> h AND ht ----------
// (frozen from R19)
__global__ __launch_bounds__(256, 2) void k_enc(
    const int* __restrict__ types, const int* __restrict__ ents,
    const int* __restrict__ vals, const int* __restrict__ haa,
    const short* __restrict__ Etp, const short* __restrict__ Eent,
    const short* __restrict__ Eval, const short* __restrict__ Eha,
    const short* __restrict__ Wt, const float* __restrict__ benc,
    short* __restrict__ h, short* __restrict__ ht, float* __restrict__ lsum) {
  __shared__ __align__(16) short lds[33280];
  __shared__ int idx[4][256];
  short* As = lds;
  short* Bs = lds + 16384;
  int t = threadIdx.x;
  if (blockIdx.x == 0) {
    f32x4v z4;
    z4[0] = z4[1] = z4[2] = z4[3] = 0.0f;
    for (int i = t; i < 8192; i += 256) *(f32x4v*)(lsum + (size_t)i * 4) = z4;
  }
  int wgid = xcd_swz(blockIdx.x, 512);
  int m0 = (wgid >> 2) * 256, n0 = (wgid & 3) * 128;
  int b_ = m0 >> 10, s0 = m0 & 1023;
  for (int i = t; i < 1024; i += 256) {
    int tb = i >> 8, rr = i & 255, g = m0 + rr;
    int v;
    if (tb == 0) v = types[g];
    else if (tb == 1) v = ents[g];
    else if (tb == 2) v = vals[g];
    else v = haa[g];
    idx[tb][rr] = v;
  }
  int lane = t & 63, wid = t >> 6, lr = lane & 31, lh = lane >> 5;
  int wm = wid >> 1, wn = wid & 1;
  f32x16v acc[4][2];
#pragma unroll
  for (int a = 0; a < 4; ++a)
#pragma unroll
    for (int bb = 0; bb < 2; ++bb) acc[a][bb] = fzero16();

  for (int kk = 0; kk < 512; kk += 64) {
    __syncthreads();
    {
      int tb = kk >> 7, koff = kk & 127;
      const short* tbl = (tb == 0) ? Etp : (tb == 1) ? Eent : (tb == 2) ? Eval : Eha;
      short* lbase = As + wid * 512;
#pragma unroll
      for (int i = 0; i < 8; ++i) {
        int row = (t >> 3) + i * 32;
        int c = (t & 7) ^ (row & 7);
        gload16(tbl + (size_t)idx[tb][row] * 128 + koff + c * 8, lbase + i * 2048);
      }
    }
    stage_rows<4>(Wt, 512, n0, kk, Bs, t);
    vmwait0();
    __syncthreads();
    mfma_block2(As, Bs, acc, lr, lh, wm, wn);
  }
  __syncthreads();
  short* tlx = lds;         // [128 n][260]: n-row holds 256 m values
#pragma unroll
  for (int a = 0; a < 4; ++a)
#pragma unroll
    for (int bb = 0; bb < 2; ++bb) {
      int col = 64 * wn + 32 * bb + lr;
      int n = n0 + col;
      float bias = benc[n];
#pragma unroll
      for (int r = 0; r < 16; ++r) {
        int rloc = 32 * a + (r & 3) + 8 * (r >> 2) + 4 * lh;
        int m = m0 + 128 * wm + rloc;
        short pb = f2bf(fmaxf(acc[a][bb][r] + bias, 0.0f));
        h[(size_t)m * 512 + n] = pb;
        tlx[col * 260 + 128 * wm + rloc] = pb;
      }
    }
  __syncthreads();
  {
    int n_loc = t >> 1, off = (t & 1) * 128;
    const short* srcl = tlx + n_loc * 260 + off;
    short* dstp = ht + (size_t)b_ * 524288 + (size_t)(n0 + n_loc) * 1024 + s0 + off;
#pragma unroll
    for (int v = 0; v < 16; ++v)
      *(bf16x8v*)(dstp + v * 8) = *(const bf16x8v*)(srcl + v * 8);
  }
}

// ---- K2a: scores + exp -> P (unnormalized, diag=0) + lsum ---------------
// (frozen from R19)
__global__ __launch_bounds__(256, 2) void k_scores(const short* __restrict__ h,
                                                   short* __restrict__ P,
                                                   float* __restrict__ lsum) {
  __shared__ __align__(16) short lds[16640];
  short* As = lds;
  short* Bs = lds + 8192;
  int t = threadIdx.x;
  int wgid = xcd_swz(blockIdx.x, 1152);
  int b = wgid / 36;
  int pid = wgid - b * 36, mt = 0;
  while (pid >= 8 - mt) { pid -= 8 - mt; ++mt; }
  int nt = mt + pid;
  int m0 = mt * 128, n0 = nt * 128;
  const short* hb = h + (size_t)b * 524288;
  int lane = t & 63, wid = t >> 6, lr = lane & 31, lh = lane >> 5;
  int wm = wid >> 1, wn = wid & 1;
  f32x16v acc[2][2];
#pragma unroll
  for (int a = 0; a < 2; ++a)
#pragma unroll
    for (int bb = 0; bb < 2; ++bb) acc[a][bb] = fzero16();

  for (int kk = 0; kk < 512; kk += 64) {
    __syncthreads();
    stage_rows<4>(hb, 512, m0, kk, As, t);
    stage_rows<4>(hb, 512, n0, kk, Bs, t);
    vmwait0();
    __syncthreads();
    mfma_block(As, Bs, acc, lr, lh, wm, wn);
  }
  __syncthreads();
  short* tl = lds;            // [128][130] bf16
  bool diag = (mt == nt);
  float* lsb = lsum + (size_t)b * 1024;
#pragma unroll
  for (int a = 0; a < 2; ++a) {
#pragma unroll
    for (int r = 0; r < 16; ++r) {
      int row_loc = 64 * wm + 32 * a + (r & 3) + 8 * (r >> 2) + 4 * lh;
      int rg = m0 + row_loc;
#pragma unroll
      for (int bb = 0; bb < 2; ++bb) {
        int j_loc = 64 * wn + 32 * bb + lr;
        int j = n0 + j_loc;
        float s = acc[a][bb][r];
        tl[row_loc * 130 + j_loc] = (j == rg) ? (short)0 : f2bf(__expf(s));
      }
    }
  }
  __syncthreads();
  {
    int row = t >> 1, half = (t & 1) * 64;
    short* dst = P + ((size_t)(b * 1024 + m0 + row)) * 1024 + n0 + half;
    const short* srcl = tl + row * 130 + half;
    float rs = 0.0f;
#pragma unroll
    for (int v = 0; v < 8; ++v) {
      bf16x8v o = *(const bf16x8v*)(srcl + v * 8);
#pragma unroll
      for (int e = 0; e < 8; ++e) rs += bf2f(o[e]);
      *(bf16x8v*)(dst + v * 8) = o;
    }
    rs += __shfl_xor(rs, 1, 64);
    if ((t & 1) == 0) atomicAdd(&lsb[m0 + row], rs);
  }
  if (!diag) {
    int jr = t >> 1, ch = (t & 1) * 64;
    short* dst = P + ((size_t)(b * 1024 + n0 + jr)) * 1024 + m0 + ch;
    float cs = 0.0f;
#pragma unroll
    for (int v = 0; v < 8; ++v) {
      bf16x8v o;
#pragma unroll
      for (int e = 0; e < 8; ++e) {
        short pv = tl[(ch + v * 8 + e) * 130 + jr];
        o[e] = pv;
        cs += bf2f(pv);
      }
      *(bf16x8v*)(dst + v * 8) = o;
    }
    cs += __shfl_xor(cs, 1, 64);
    if ((t & 1) == 0) atomicAdd(&lsb[n0 + jr], cs);
  }
}

// ---- K2b: ctx = (P @ h_b) / l — 8-wave counted-vmcnt pipeline -----------
// 256x256 tile, 512 thr, 2x64KB dbuf, grid 256 (1 block/CU), XCD-swizzled.
__global__ __launch_bounds__(512) void k_ctx(const short* __restrict__ P,
                                             const short* __restrict__ ht,
                                             const float* __restrict__ lsum,
                                             short* __restrict__ ctx) {
  extern __shared__ __align__(16) short plds[];  // 2 x 32768 shorts
  int t = threadIdx.x;
  int wgid = xcd_swz(blockIdx.x, 256);
  int b = wgid >> 3, mt = (wgid >> 1) & 3, nt = wgid & 1;
  int m0 = mt * 256, n0 = nt * 256;
  int lane = t & 63, wid = t >> 6, lr = lane & 31, lh = lane >> 5;
  int wm = wid >> 2, wn = wid & 3;
  f32x16v acc[4][2];
#pragma unroll
  for (int a = 0; a < 4; ++a)
#pragma unroll
    for (int bb = 0; bb < 2; ++bb) acc[a][bb] = fzero16();

  const short* Pb = P + (size_t)b * 1048576;
  const short* htb = ht + (size_t)b * 524288;
  auto issueT = [&](int kt) {
    short* buf = plds + (kt & 1) * 32768;
    int kk = kt * 64;
    stage512<4>(Pb, 1024, m0, kk, buf, t);
    stage512<4>(htb, 1024, n0, kk, buf + 16384, t);
  };
  issueT(0);
  issueT(1);
  for (int kt = 0; kt < 16; ++kt) {
    if (kt < 15) vmwait8(); else vmwait0();
    __builtin_amdgcn_s_barrier();
    __builtin_amdgcn_sched_barrier(0);
    short* buf = plds + (kt & 1) * 32768;
    __builtin_amdgcn_s_setprio(1);
    mfma_block2(buf, buf + 16384, acc, lr, lh, wm, wn);
    __builtin_amdgcn_s_setprio(0);
    __builtin_amdgcn_s_barrier();
    __builtin_amdgcn_sched_barrier(0);
    if (kt + 2 < 16) issueT(kt + 2);
  }
#pragma unroll
  for (int a = 0; a < 4; ++a)
#pragma unroll
    for (int r = 0; r < 16; ++r) {
      int m = m0 + 128 * wm + 32 * a + (r & 3) + 8 * (r >> 2) + 4 * lh;
      float linv = 1.0f / lsum[(size_t)b * 1024 + m];
#pragma unroll
      for (int bb = 0; bb < 2; ++bb) {
        int n = n0 + 64 * wn + 32 * bb + lr;
        ctx[((size_t)(b * 1024 + m)) * 512 + n] = f2bf(acc[a][bb][r] * linv);
      }
    }
}

// ---- K3: gate GEMM — 8-wave counted-vmcnt pipeline ----------------------
// 256x256 tile, 512 thr, grid 256 (1 block/CU), XCD-swizzled n-fastest.
__global__ __launch_bounds__(512) void k_gate(const short* __restrict__ h,
                                              const short* __restrict__ ctx,
                                              const short* __restrict__ Wgt,
                                              const float* __restrict__ bg,
                                              float* __restrict__ out,
                                              float* __restrict__ part) {
  extern __shared__ __align__(16) short plds[];  // 2 x 32768 shorts
  __shared__ float partc[2][256];
  int t = threadIdx.x;
  int wgid = xcd_swz(blockIdx.x, 256);
  int m0 = (wgid >> 1) * 256, n0 = (wgid & 1) * 256;
  int lane = t & 63, wid = t >> 6, lr = lane & 31, lh = lane >> 5;
  int wm = wid >> 2, wn = wid & 3;
  f32x16v acc[4][2];
#pragma unroll
  for (int a = 0; a < 4; ++a)
#pragma unroll
    for (int bb = 0; bb < 2; ++bb) acc[a][bb] = fzero16();

  auto issueT = [&](int kt) {
    short* buf = plds + (kt & 1) * 32768;
    int kk = kt * 64;
    const short* Asrc = (kk < 512) ? h : ctx;
    stage512<4>(Asrc, 512, m0, kk & 511, buf, t);
    stage512<4>(Wgt, 1024, n0, kk, buf + 16384, t);
  };
  issueT(0);
  issueT(1);
  for (int kt = 0; kt < 16; ++kt) {
    if (kt < 15) vmwait8(); else vmwait0();
    __builtin_amdgcn_s_barrier();
    __builtin_amdgcn_sched_barrier(0);
    short* buf = plds + (kt & 1) * 32768;
    __builtin_amdgcn_s_setprio(1);
    mfma_block2(buf, buf + 16384, acc, lr, lh, wm, wn);
    __builtin_amdgcn_s_setprio(0);
    __builtin_amdgcn_s_barrier();
    __builtin_amdgcn_sched_barrier(0);
    if (kt + 2 < 16) issueT(kt + 2);
  }
  float cs[2] = {0.0f, 0.0f};
#pragma unroll
  for (int a = 0; a < 4; ++a)
#pragma unroll
    for (int bb = 0; bb < 2; ++bb) {
      int n = n0 + 64 * wn + 32 * bb + lr;
      float bias = bg[n];
#pragma unroll
      for (int r = 0; r < 16; ++r) {
        int m = m0 + 128 * wm + 32 * a + (r & 3) + 8 * (r >> 2) + 4 * lh;
        float x = acc[a][bb][r] + bias;
        float g = 1.0f / (1.0f + __expf(-x));
        float hv = bf2f(h[(size_t)m * 512 + n]);
        float o = g * hv;
        out[(size_t)m * 512 + n] = o;
        cs[bb] += o;
      }
    }
  // column partial sums: wave wm covers rows [m0+128*wm, +128) = one s-block
#pragma unroll
  for (int bb = 0; bb < 2; ++bb) {
    cs[bb] += __shfl_xor(cs[bb], 32, 64);
    if (lh == 0) partc[wm][64 * wn + 32 * bb + lr] = cs[bb];
  }
  __syncthreads();
  {
    int half = t >> 8, col = t & 255;
    int b = m0 >> 10, si = ((m0 >> 7) & 7) + half;
    part[(size_t)(si * 32 + b) * 512 + n0 + col] = partc[half][col];
  }
}

// ---- K4: final means, written as 4 identical outputs --------------------
__global__ __launch_bounds__(512) void k_avg_fin(const float* __restrict__ part,
                                                 float* __restrict__ avg) {
  int b = blockIdx.x, n = threadIdx.x;
  float s = 0.0f;
#pragma unroll
  for (int si = 0; si < 8; ++si) s += part[(size_t)(si * 32 + b) * 512 + n];
  s *= (1.0f / 1024.0f);
#pragma unroll
  for (int i = 0; i < 4; ++i) avg[(size_t)i * 16384 + b * 512 + n] = s;
}

// ---- workspace layout (bytes) -------------------------------------------
#define WS_H 0
#define WS_HT 33554432
#define WS_CTX 67108864          // also hosts bf16 tables until k_enc is done
#define WS_LSUM 100663296
#define WS_WT 100794368
#define WS_WGT 101318656
#define WS_PART 102367232
// total required: 102,891,520 bytes (~98.1 MiB)
// bf16 tables inside the CTX region (dead until k_ctx writes it):
#define CTX_ETP 0
#define CTX_EENT 10240
#define CTX_EVAL 7690240
#define CTX_EHA 15370240

extern "C" void kernel_launch(void* const* d_in, const int* in_sizes, int n_in,
                              void* d_out, int out_size, void* d_ws, size_t ws_size,
                              hipStream_t stream) {
  const int* types = (const int*)d_in[0];
  const int* ents = (const int*)d_in[1];
  const int* vals = (const int*)d_in[2];
  const int* haa = (const int*)d_in[3];
  const float* E_tp = (const float*)d_in[4];
  const float* E_ent = (const float*)d_in[5];
  const float* E_val = (const float*)d_in[6];
  const float* E_ha = (const float*)d_in[7];
  const float* W_enc = (const float*)d_in[8];
  const float* benc = (const float*)d_in[9];
  const float* W_g = (const float*)d_in[10];
  const float* bg = (const float*)d_in[11];
  float* out = (float*)d_out;

  char* ws = (char*)d_ws;
  short* h = (short*)(ws + WS_H);        // bf16 [32768][512]
  short* ht = (short*)(ws + WS_HT);      // bf16 [32][512][1024]
  short* ctx = (short*)(ws + WS_CTX);    // bf16 [32768][512]
  float* lsum = (float*)(ws + WS_LSUM);  // f32  [32][1024]
  short* Wt = (short*)(ws + WS_WT);      // bf16 [512][512]   (W_enc^T)
  short* Wgt = (short*)(ws + WS_WGT);    // bf16 [512][1024]  (W_g^T)
  float* part = (float*)(ws + WS_PART);  // f32  [8][32][512]
  short* P = (short*)d_out;              // bf16 [32][1024][1024] in content region
  short* Etp = (short*)(ws + WS_CTX + CTX_ETP);
  short* Eent = (short*)(ws + WS_CTX + CTX_EENT);
  short* Eval = (short*)(ws + WS_CTX + CTX_EVAL);
  short* Eha = (short*)(ws + WS_CTX + CTX_EHA);

  hipFuncSetAttribute((const void*)k_ctx,
                      hipFuncAttributeMaxDynamicSharedMemorySize, PIPE2_LDS);
  hipFuncSetAttribute((const void*)k_gate,
                      hipFuncAttributeMaxDynamicSharedMemorySize, PIPE2_LDS);

  k_prep<<<dim3(4521), 256, 0, stream>>>(E_tp, Etp, E_ent, Eent, E_val, Eval,
                                         E_ha, Eha, W_enc, Wt, W_g, Wgt);
  k_enc<<<dim3(512), 256, 0, stream>>>(types, ents, vals, haa, Etp, Eent, Eval,
                                       Eha, Wt, benc, h, ht, lsum);
  k_scores<<<dim3(1152), 256, 0, stream>>>(h, P, lsum);
  k_ctx<<<dim3(256), 512, PIPE2_LDS, stream>>>(P, ht, lsum, ctx);
  k_gate<<<dim3(256), 512, PIPE2_LDS, stream>>>(h, ctx, Wgt, bg, out, part);
  k_avg_fin<<<dim3(32), 512, 0, stream>>>(part, out + 16777216);
}